// Round 17
// baseline (121.248 us; speedup 1.0000x reference)
//
#include <hip/hip_runtime.h>
#include <hip/hip_fp16.h>

#define NROWS 4096
#define HID 64

typedef _Float16 f16x8 __attribute__((ext_vector_type(8)));
typedef float f32x4 __attribute__((ext_vector_type(4)));

static __device__ __forceinline__ __half2 u2h(unsigned u) {
  __half2 h; __builtin_memcpy(&h, &u, 4); return h;
}
static __device__ __forceinline__ unsigned h2u(__half2 h) {
  unsigned u; __builtin_memcpy(&u, &h, 4); return u;
}

// ---------------- kernel 1: x=in@emb_w+b; qh=(x@q_w+b)*0.125 fp16;
//                  kh=(x@k_w+b) fp16 row-major; opk pack. 4 rows/block. ----
__global__ __launch_bounds__(256) void k_embed(
    const float* __restrict__ inp, const float* __restrict__ emb_w,
    const float* __restrict__ emb_b, const float* __restrict__ q_w,
    const float* __restrict__ q_b, const float* __restrict__ k_w,
    const float* __restrict__ k_b, __half* __restrict__ qh,
    __half* __restrict__ kh, float* __restrict__ opk) {
  int t = threadIdx.x;
  int rr = t >> 6;           // 0..3 sub-row
  int c = t & 63;            // col
  int row = blockIdx.x * 4 + rr;
  __shared__ float in_s[4][8];
  __shared__ float x_s[4][64];
  if (c < 8) in_s[rr][c] = inp[row * 8 + c];
  __syncthreads();
  float acc = emb_b[c];
#pragma unroll
  for (int i = 0; i < 8; ++i) acc += in_s[rr][i] * emb_w[i * 64 + c];
  x_s[rr][c] = acc;
  __syncthreads();
  float qa = q_b[c], ka = k_b[c];
#pragma unroll
  for (int i = 0; i < 64; ++i) {
    float xv = x_s[rr][i];
    qa += xv * q_w[i * 64 + c];
    ka += xv * k_w[i * 64 + c];
  }
  qh[row * 64 + c] = __float2half(qa * 0.125f);  // fold 1/sqrt(64)
  kh[row * 64 + c] = __float2half(ka);
  if (c < 4) opk[row * 4 + c] = inp[row * 8 + 4 + c];
}

// ---------------- kernel 2: MFMA scores + softmax (512 thr, r13/r15) ------
__global__ __launch_bounds__(512, 2) void k_scores(
    const __half* __restrict__ qh, const __half* __restrict__ kh,
    float* __restrict__ S) {
  __shared__ float redm[8][16];
  __shared__ float reds[8][16];
  int t = threadIdx.x;
  int w = t >> 6;
  int l = t & 63;
  int m16 = l & 15;
  int g4 = l >> 4;
  int rb = blockIdx.x * 16;
  const uint4* qq = (const uint4*)qh;
  const uint4* kk = (const uint4*)kh;
  int qrow = rb + m16;
  f16x8 a0 = __builtin_bit_cast(f16x8, qq[qrow * 8 + g4]);
  f16x8 a1 = __builtin_bit_cast(f16x8, qq[qrow * 8 + 4 + g4]);
  f32x4 acc[32];
#pragma unroll
  for (int i = 0; i < 32; ++i) acc[i] = (f32x4){0.f, 0.f, 0.f, 0.f};
#pragma unroll
  for (int i = 0; i < 32; ++i) {
    int kcol = (w * 32 + i) * 16 + m16;
    f16x8 b0 = __builtin_bit_cast(f16x8, kk[kcol * 8 + g4]);
    f16x8 b1 = __builtin_bit_cast(f16x8, kk[kcol * 8 + 4 + g4]);
    acc[i] = __builtin_amdgcn_mfma_f32_16x16x32_f16(a0, b0, acc[i], 0, 0, 0);
    acc[i] = __builtin_amdgcn_mfma_f32_16x16x32_f16(a1, b1, acc[i], 0, 0, 0);
  }
  float m4[4] = {-1e30f, -1e30f, -1e30f, -1e30f};
#pragma unroll
  for (int i = 0; i < 32; ++i) {
#pragma unroll
    for (int c = 0; c < 4; ++c) m4[c] = fmaxf(m4[c], acc[i][c]);
  }
#pragma unroll
  for (int off = 1; off < 16; off <<= 1) {
#pragma unroll
    for (int c = 0; c < 4; ++c) m4[c] = fmaxf(m4[c], __shfl_xor(m4[c], off, 64));
  }
  if (m16 == 0) {
#pragma unroll
    for (int c = 0; c < 4; ++c) redm[w][g4 * 4 + c] = m4[c];
  }
  __syncthreads();
#pragma unroll
  for (int c = 0; c < 4; ++c) {
    float mm = redm[0][g4 * 4 + c];
#pragma unroll
    for (int ww = 1; ww < 8; ++ww) mm = fmaxf(mm, redm[ww][g4 * 4 + c]);
    m4[c] = mm;
  }
  float s4[4] = {0.f, 0.f, 0.f, 0.f};
#pragma unroll
  for (int i = 0; i < 32; ++i) {
#pragma unroll
    for (int c = 0; c < 4; ++c) {
      float e = __expf(acc[i][c] - m4[c]);
      acc[i][c] = e;
      s4[c] += e;
    }
  }
#pragma unroll
  for (int off = 1; off < 16; off <<= 1) {
#pragma unroll
    for (int c = 0; c < 4; ++c) s4[c] += __shfl_xor(s4[c], off, 64);
  }
  if (m16 == 0) {
#pragma unroll
    for (int c = 0; c < 4; ++c) reds[w][g4 * 4 + c] = s4[c];
  }
  __syncthreads();
  float li[4];
#pragma unroll
  for (int c = 0; c < 4; ++c) {
    float ss = reds[0][g4 * 4 + c];
#pragma unroll
    for (int ww = 1; ww < 8; ++ww) ss += reds[ww][g4 * 4 + c];
    li[c] = 1.0f / ss;
  }
#pragma unroll
  for (int i = 0; i < 32; ++i) {
    int col = (w * 32 + i) * 16 + m16;
#pragma unroll
    for (int c = 0; c < 4; ++c) {
      S[(size_t)(rb + g4 * 4 + c) * NROWS + col] = acc[i][c] * li[c];
    }
  }
}

// ---------------- kernel 3: conv5b — fp16 in-place, 256x74 tile -----------
// conv5 structure with 9 rows/wave (rb=1+9w, rows 1..73), 74 staged rows.
// LDS 38.5 KB -> still 4 blocks/CU. Redundancy 1.56 -> 1.49.
// Boundary rows (rb, rb+8) deferred between two barriers (proof as before:
// wave w-1 reads at most row rb; wave w+1 reads from rb+8).
// Valid region shrinks 1/layer: interior rows [10,64) x cols [10,246).
#define C5D 130   // dword stride per row (128 data + 2 pad)
#define C5H 74    // staged rows
#define C5OW 236
#define C5OH 54
#define C5GX 18   // ceil(4096/236)
#define C5GY 76   // ceil(4096/54)

__global__ __launch_bounds__(512, 2) void k_conv5(
    const float* __restrict__ attn, float* __restrict__ partial,
    const float* __restrict__ w1p, const float* __restrict__ w2p,
    const float* __restrict__ ap, const float* __restrict__ opk) {
  __shared__ unsigned buf[C5H * C5D];  // 38.5 KB
  int tid = threadIdx.x;
  int bx = blockIdx.x, by = blockIdx.y;
  int gi0 = by * C5OH - 10;
  int gj0 = bx * C5OW - 10;
  bool edge = (bx == 0) || (bx == C5GX - 1) || (by == 0) || (by == C5GY - 1);
  // ---- stage: fp32 -> fp16 x256 ----
  if (!edge) {
    for (int idx = tid; idx < C5H * 128; idx += 512) {
      int r = idx >> 7, d = idx & 127;
      float2 v = *(const float2*)(attn + (size_t)(gi0 + r) * NROWS + gj0 + 2 * d);
      buf[r * C5D + d] =
          h2u(__float22half2_rn(make_float2(v.x * 256.f, v.y * 256.f)));
    }
  } else {
    for (int idx = tid; idx < C5H * 128; idx += 512) {
      int r = idx >> 7, d = idx & 127;
      int gi = gi0 + r, gj = gj0 + 2 * d;
      float a = 0.f, b = 0.f;
      if ((unsigned)gi < (unsigned)NROWS) {
        if ((unsigned)gj < (unsigned)NROWS) a = attn[(size_t)gi * NROWS + gj] * 256.f;
        if ((unsigned)(gj + 1) < (unsigned)NROWS) b = attn[(size_t)gi * NROWS + gj + 1] * 256.f;
      }
      buf[r * C5D + d] = h2u(__float22half2_rn(make_float2(a, b)));
    }
  }
  __syncthreads();

  int wv = tid >> 6, l = tid & 63;
  int rb = 1 + 9 * wv;   // rows rb..rb+8; 8 waves cover rows [1,73)
  int doff = 2 * l;      // dword offset (cols 4l..4l+3)
  __half2 CM0 = __float2half2_rn(1.f), CM1 = __float2half2_rn(1.f);
  if (edge) {
    float m0 = ((unsigned)(gj0 + 4 * l + 0) < (unsigned)NROWS) ? 1.f : 0.f;
    float m1 = ((unsigned)(gj0 + 4 * l + 1) < (unsigned)NROWS) ? 1.f : 0.f;
    float m2 = ((unsigned)(gj0 + 4 * l + 2) < (unsigned)NROWS) ? 1.f : 0.f;
    float m3 = ((unsigned)(gj0 + 4 * l + 3) < (unsigned)NROWS) ? 1.f : 0.f;
    CM0 = __float22half2_rn(make_float2(m0, m1));
    CM1 = __float22half2_rn(make_float2(m2, m3));
  }

  for (int p = 0; p < 10; ++p) {
    __half2 W10 = __float2half2_rn(w1p[3 * p]);
    __half2 W12 = __float2half2_rn(w1p[3 * p + 2]);
    __half2 WC  = __float2half2_rn(w1p[3 * p + 1] + w2p[3 * p + 1]);
    __half2 W20 = __float2half2_rn(w2p[3 * p]);
    __half2 W22 = __float2half2_rn(w2p[3 * p + 2]);
    __half2 AL  = __float2half2_rn(ap[p]);
    uint2 Vm = *(uint2*)&buf[(rb - 1) * C5D + doff];
    uint2 Vc = *(uint2*)&buf[rb * C5D + doff];
    uint2 dfirst, dlast;
#pragma unroll
    for (int s = 0; s < 9; ++s) {
      int r = rb + s;
      uint2 Vp = *(uint2*)&buf[(r + 1) * C5D + doff];
      unsigned Lm1 = (unsigned)__builtin_amdgcn_update_dpp(
          0, (int)Vc.y, 0x138, 0xF, 0xF, true);  // wave_shr1: lane l-1 top
      unsigned Hp1 = (unsigned)__builtin_amdgcn_update_dpp(
          0, (int)Vc.x, 0x130, 0xF, 0xF, true);  // wave_shl1: lane l+1 bottom
      unsigned SL0 = __builtin_amdgcn_alignbit(Vc.x, Lm1, 16);
      unsigned SR0 = __builtin_amdgcn_alignbit(Vc.y, Vc.x, 16);
      unsigned SR1 = __builtin_amdgcn_alignbit(Hp1, Vc.y, 16);
      __half2 o0 = __hmul2(WC, u2h(Vc.x));
      o0 = __hfma2(W10, u2h(SL0), o0);
      o0 = __hfma2(W12, u2h(SR0), o0);
      o0 = __hfma2(W20, u2h(Vm.x), o0);
      o0 = __hfma2(W22, u2h(Vp.x), o0);
      __half2 o1 = __hmul2(WC, u2h(Vc.y));
      o1 = __hfma2(W10, u2h(SR0), o1);
      o1 = __hfma2(W12, u2h(SR1), o1);
      o1 = __hfma2(W20, u2h(Vm.y), o1);
      o1 = __hfma2(W22, u2h(Vp.y), o1);
      // leaky relu = max(x, a*x), 0<a<1, via v_pk_max_f16
      {
        unsigned u0 = h2u(o0), ua0 = h2u(__hmul2(AL, o0)), r0;
        asm("v_pk_max_f16 %0, %1, %2" : "=v"(r0) : "v"(u0), "v"(ua0));
        o0 = u2h(r0);
        unsigned u1 = h2u(o1), ua1 = h2u(__hmul2(AL, o1)), r1;
        asm("v_pk_max_f16 %0, %1, %2" : "=v"(r1) : "v"(u1), "v"(ua1));
        o1 = u2h(r1);
      }
      if (edge) {
        o0 = __hmul2(o0, CM0);
        o1 = __hmul2(o1, CM1);
        if ((unsigned)(gi0 + r) >= (unsigned)NROWS) {
          o0 = __float2half2_rn(0.f);
          o1 = __float2half2_rn(0.f);
        }
      }
      uint2 res = {h2u(o0), h2u(o1)};
      if (s == 0) dfirst = res;
      else if (s == 8) dlast = res;
      else *(uint2*)&buf[r * C5D + doff] = res;  // interior: own-wave only
      Vm = Vc; Vc = Vp;
    }
    __syncthreads();  // all old-value reads complete
    *(uint2*)&buf[rb * C5D + doff] = dfirst;
    *(uint2*)&buf[(rb + 8) * C5D + doff] = dlast;
    __syncthreads();  // boundary rows visible for next layer
  }

  // ---- epilogue: masked dot over interior rows [10,64), cols [10,246) ----
  const unsigned* fin = buf;
  int i = tid >> 3;    // 0..63 (54 used)
  int part = tid & 7;  // 8 lanes per row
  int gi = gi0 + 10 + i;
  float a0 = 0.f, a1 = 0.f, a2 = 0.f, a3 = 0.f;
  if (i < C5OH && gi < NROWS) {
    const float4* op = (const float4*)opk;
    for (int g = part; g < 59; g += 8) {
      int jc = 10 + 4 * g;
      int gj = gj0 + jc;  // = bx*236 + 4g >= 0, multiple of 4
      if (gj + 3 < NROWS) {
        unsigned d0 = fin[(10 + i) * C5D + (jc >> 1)];
        unsigned d1 = fin[(10 + i) * C5D + (jc >> 1) + 1];
        __half2 h0 = u2h(d0), h1 = u2h(d1);
        float4 av = *(const float4*)(attn + (size_t)gi * NROWS + gj);
        if (__low2float(h0) > 0.f)  { float4 o = op[gj + 0]; a0 += av.x * o.x; a1 += av.x * o.y; a2 += av.x * o.z; a3 += av.x * o.w; }
        if (__high2float(h0) > 0.f) { float4 o = op[gj + 1]; a0 += av.y * o.x; a1 += av.y * o.y; a2 += av.y * o.z; a3 += av.y * o.w; }
        if (__low2float(h1) > 0.f)  { float4 o = op[gj + 2]; a0 += av.z * o.x; a1 += av.z * o.y; a2 += av.z * o.z; a3 += av.z * o.w; }
        if (__high2float(h1) > 0.f) { float4 o = op[gj + 3]; a0 += av.w * o.x; a1 += av.w * o.y; a2 += av.w * o.z; a3 += av.w * o.w; }
      }
    }
  }
#pragma unroll
  for (int off = 1; off < 8; off <<= 1) {
    a0 += __shfl_xor(a0, off, 64);
    a1 += __shfl_xor(a1, off, 64);
    a2 += __shfl_xor(a2, off, 64);
    a3 += __shfl_xor(a3, off, 64);
  }
  if (part == 0 && i < C5OH && gi < NROWS) {
    float4 r = {a0, a1, a2, a3};
    *(float4*)&partial[((size_t)bx * NROWS + gi) * 4] = r;
  }
}

// ---------------- kernel 4: reduce 18 partials + gcn + mlp head -----------
__global__ __launch_bounds__(64) void k_head(
    const float* __restrict__ partial, const float* __restrict__ gcn_w,
    const float* __restrict__ gcn_b, const float* __restrict__ gcn_a,
    const float* __restrict__ w1, const float* __restrict__ b1,
    const float* __restrict__ w2, const float* __restrict__ b2,
    float* __restrict__ out) {
  int row = blockIdx.x;
  int t = threadIdx.x;  // 64
  __shared__ float c4[4];
  __shared__ float gs[64];
  __shared__ float ms[32];
  {
    int c = t & 3, gg = t >> 2;  // gg in [0,16)
    float s = partial[((size_t)gg * NROWS + row) * 4 + c];
    if (gg < C5GX - 16)
      s += partial[((size_t)(gg + 16) * NROWS + row) * 4 + c];
#pragma unroll
    for (int off = 4; off < 64; off <<= 1) s += __shfl_xor(s, off, 64);
    if (t < 4) c4[t] = s;
  }
  __syncthreads();
  float g = gcn_b[t];
#pragma unroll
  for (int d = 0; d < 4; ++d) g += c4[d] * gcn_w[d * 64 + t];
  float ga = gcn_a[0];
  gs[t] = (g >= 0.f) ? g : ga * g;
  __syncthreads();
  if (t < 32) {
    float mm = b1[t];
#pragma unroll
    for (int i = 0; i < 64; ++i) mm += gs[i] * w1[i * 32 + t];
    ms[t] = fmaxf(mm, 0.f);
  }
  __syncthreads();
  if (t < 4) {
    float o = b2[t];
#pragma unroll
    for (int i = 0; i < 32; ++i) o += ms[i] * w2[i * 4 + t];
    out[row * 4 + t] = o;
  }
}

extern "C" void kernel_launch(void* const* d_in, const int* in_sizes, int n_in,
                              void* d_out, int out_size, void* d_ws, size_t ws_size,
                              hipStream_t stream) {
  (void)in_sizes; (void)n_in; (void)out_size; (void)ws_size;
  const float* inp    = (const float*)d_in[0];
  const float* emb_w  = (const float*)d_in[1];
  const float* emb_b  = (const float*)d_in[2];
  const float* q_w    = (const float*)d_in[3];
  const float* q_b    = (const float*)d_in[4];
  const float* k_w    = (const float*)d_in[5];
  const float* k_b    = (const float*)d_in[6];
  const float* conv_w1 = (const float*)d_in[7];
  const float* conv_w2 = (const float*)d_in[8];
  const float* conv_a  = (const float*)d_in[9];
  const float* gcn_w  = (const float*)d_in[10];
  const float* gcn_b  = (const float*)d_in[11];
  const float* gcn_a  = (const float*)d_in[12];
  const float* mlp_w1 = (const float*)d_in[13];
  const float* mlp_b1 = (const float*)d_in[14];
  const float* mlp_w2 = (const float*)d_in[15];
  const float* mlp_b2 = (const float*)d_in[16];
  float* out = (float*)d_out;

  const size_t NN = (size_t)NROWS * NROWS;
  float* A       = (float*)d_ws;                      // 4096^2 attn
  float* partial = A + NN;                            // 18*4096*4
  float* qhf     = partial + (size_t)18 * NROWS * 4;
  float* khf     = qhf + (size_t)NROWS * HID / 2;     // fp16 buffers
  float* opk     = khf + (size_t)NROWS * HID / 2;

  k_embed<<<NROWS / 4, 256, 0, stream>>>(inp, emb_w, emb_b, q_w, q_b, k_w, k_b,
                                         (__half*)qhf, (__half*)khf, opk);
  k_scores<<<NROWS / 16, 512, 0, stream>>>((const __half*)qhf,
                                           (const __half*)khf, A);
  k_conv5<<<dim3(C5GX, C5GY), 512, 0, stream>>>(A, partial, conv_w1, conv_w2,
                                                conv_a, opk);
  k_head<<<NROWS, 64, 0, stream>>>(partial, gcn_w, gcn_b, gcn_a, mlp_w1, mlp_b1,
                                   mlp_w2, mlp_b2, out);
}

// Round 18
// 109.997 us; speedup vs baseline: 1.1023x; 1.1023x over previous
//
#include <hip/hip_runtime.h>
#include <hip/hip_fp16.h>

#define NROWS 4096
#define HID 64

typedef _Float16 f16x8 __attribute__((ext_vector_type(8)));
typedef float f32x4 __attribute__((ext_vector_type(4)));

static __device__ __forceinline__ __half2 u2h(unsigned u) {
  __half2 h; __builtin_memcpy(&h, &u, 4); return h;
}
static __device__ __forceinline__ unsigned h2u(__half2 h) {
  unsigned u; __builtin_memcpy(&u, &h, 4); return u;
}

// ---------------- kernel 1: x=in@emb_w+b; qh=(x@q_w+b)*0.125 fp16;
//                  kh=(x@k_w+b) fp16 row-major; opk pack. 4 rows/block. ----
__global__ __launch_bounds__(256) void k_embed(
    const float* __restrict__ inp, const float* __restrict__ emb_w,
    const float* __restrict__ emb_b, const float* __restrict__ q_w,
    const float* __restrict__ q_b, const float* __restrict__ k_w,
    const float* __restrict__ k_b, __half* __restrict__ qh,
    __half* __restrict__ kh, float* __restrict__ opk) {
  int t = threadIdx.x;
  int rr = t >> 6;           // 0..3 sub-row
  int c = t & 63;            // col
  int row = blockIdx.x * 4 + rr;
  __shared__ float in_s[4][8];
  __shared__ float x_s[4][64];
  if (c < 8) in_s[rr][c] = inp[row * 8 + c];
  __syncthreads();
  float acc = emb_b[c];
#pragma unroll
  for (int i = 0; i < 8; ++i) acc += in_s[rr][i] * emb_w[i * 64 + c];
  x_s[rr][c] = acc;
  __syncthreads();
  float qa = q_b[c], ka = k_b[c];
#pragma unroll
  for (int i = 0; i < 64; ++i) {
    float xv = x_s[rr][i];
    qa += xv * q_w[i * 64 + c];
    ka += xv * k_w[i * 64 + c];
  }
  qh[row * 64 + c] = __float2half(qa * 0.125f);  // fold 1/sqrt(64)
  kh[row * 64 + c] = __float2half(ka);
  if (c < 4) opk[row * 4 + c] = inp[row * 8 + 4 + c];
}

// ---------------- kernel 2: MFMA scores + softmax -> fp16 x256 attn -------
// 256 blocks x 512 thr. Stores attn as fp16 scaled by 256 (the exact value
// conv staged before), halving the write and conv's re-read.
__global__ __launch_bounds__(512, 2) void k_scores(
    const __half* __restrict__ qh, const __half* __restrict__ kh,
    __half* __restrict__ Sh) {
  __shared__ float redm[8][16];
  __shared__ float reds[8][16];
  int t = threadIdx.x;
  int w = t >> 6;
  int l = t & 63;
  int m16 = l & 15;
  int g4 = l >> 4;
  int rb = blockIdx.x * 16;
  const uint4* qq = (const uint4*)qh;
  const uint4* kk = (const uint4*)kh;
  int qrow = rb + m16;
  f16x8 a0 = __builtin_bit_cast(f16x8, qq[qrow * 8 + g4]);
  f16x8 a1 = __builtin_bit_cast(f16x8, qq[qrow * 8 + 4 + g4]);
  f32x4 acc[32];
#pragma unroll
  for (int i = 0; i < 32; ++i) acc[i] = (f32x4){0.f, 0.f, 0.f, 0.f};
#pragma unroll
  for (int i = 0; i < 32; ++i) {
    int kcol = (w * 32 + i) * 16 + m16;
    f16x8 b0 = __builtin_bit_cast(f16x8, kk[kcol * 8 + g4]);
    f16x8 b1 = __builtin_bit_cast(f16x8, kk[kcol * 8 + 4 + g4]);
    acc[i] = __builtin_amdgcn_mfma_f32_16x16x32_f16(a0, b0, acc[i], 0, 0, 0);
    acc[i] = __builtin_amdgcn_mfma_f32_16x16x32_f16(a1, b1, acc[i], 0, 0, 0);
  }
  float m4[4] = {-1e30f, -1e30f, -1e30f, -1e30f};
#pragma unroll
  for (int i = 0; i < 32; ++i) {
#pragma unroll
    for (int c = 0; c < 4; ++c) m4[c] = fmaxf(m4[c], acc[i][c]);
  }
#pragma unroll
  for (int off = 1; off < 16; off <<= 1) {
#pragma unroll
    for (int c = 0; c < 4; ++c) m4[c] = fmaxf(m4[c], __shfl_xor(m4[c], off, 64));
  }
  if (m16 == 0) {
#pragma unroll
    for (int c = 0; c < 4; ++c) redm[w][g4 * 4 + c] = m4[c];
  }
  __syncthreads();
#pragma unroll
  for (int c = 0; c < 4; ++c) {
    float mm = redm[0][g4 * 4 + c];
#pragma unroll
    for (int ww = 1; ww < 8; ++ww) mm = fmaxf(mm, redm[ww][g4 * 4 + c]);
    m4[c] = mm;
  }
  float s4[4] = {0.f, 0.f, 0.f, 0.f};
#pragma unroll
  for (int i = 0; i < 32; ++i) {
#pragma unroll
    for (int c = 0; c < 4; ++c) {
      float e = __expf(acc[i][c] - m4[c]);
      acc[i][c] = e;
      s4[c] += e;
    }
  }
#pragma unroll
  for (int off = 1; off < 16; off <<= 1) {
#pragma unroll
    for (int c = 0; c < 4; ++c) s4[c] += __shfl_xor(s4[c], off, 64);
  }
  if (m16 == 0) {
#pragma unroll
    for (int c = 0; c < 4; ++c) reds[w][g4 * 4 + c] = s4[c];
  }
  __syncthreads();
  float li[4];
#pragma unroll
  for (int c = 0; c < 4; ++c) {
    float ss = reds[0][g4 * 4 + c];
#pragma unroll
    for (int ww = 1; ww < 8; ++ww) ss += reds[ww][g4 * 4 + c];
    li[c] = 256.0f / ss;  // fold x256 fp16 staging scale
  }
#pragma unroll
  for (int i = 0; i < 32; ++i) {
    int col = (w * 32 + i) * 16 + m16;
#pragma unroll
    for (int c = 0; c < 4; ++c) {
      Sh[(size_t)(rb + g4 * 4 + c) * NROWS + col] = __float2half(acc[i][c] * li[c]);
    }
  }
}

// ---------------- kernel 3: conv5 — fp16 in-place, 256x66, fp16 source ----
// r15 geometry (proven 78.7us): 8 rows/wave, 66 staged rows, 34.3 KB LDS,
// 4 blocks/CU. Stage is now a pure dword copy (attn already fp16 x256).
// Epilogue reads fp16 attn; 1/256 folded into partial write.
#define C5D 130   // dword stride per row (128 data + 2 pad)
#define C5H 66    // staged rows
#define C5OW 236
#define C5OH 46
#define C5GX 18   // ceil(4096/236)
#define C5GY 90   // ceil(4096/46)

__global__ __launch_bounds__(512, 2) void k_conv5(
    const __half* __restrict__ attnh, float* __restrict__ partial,
    const float* __restrict__ w1p, const float* __restrict__ w2p,
    const float* __restrict__ ap, const float* __restrict__ opk) {
  __shared__ unsigned buf[C5H * C5D];  // 34.3 KB
  const unsigned* Shd = (const unsigned*)attnh;  // dword view (2 halves)
  int tid = threadIdx.x;
  int bx = blockIdx.x, by = blockIdx.y;
  int gi0 = by * C5OH - 10;
  int gj0 = bx * C5OW - 10;   // even
  bool edge = (bx == 0) || (bx == C5GX - 1) || (by == 0) || (by == C5GY - 1);
  // ---- stage: dword copy of fp16 x256 attn ----
  if (!edge) {
    int dbase = gj0 >> 1;
    for (int idx = tid; idx < C5H * 128; idx += 512) {
      int r = idx >> 7, d = idx & 127;
      buf[r * C5D + d] = Shd[(size_t)(gi0 + r) * (NROWS / 2) + dbase + d];
    }
  } else {
    for (int idx = tid; idx < C5H * 128; idx += 512) {
      int r = idx >> 7, d = idx & 127;
      int gi = gi0 + r, gj = gj0 + 2 * d;
      __half a = __float2half(0.f), b = a;
      if ((unsigned)gi < (unsigned)NROWS) {
        if ((unsigned)gj < (unsigned)NROWS) a = attnh[(size_t)gi * NROWS + gj];
        if ((unsigned)(gj + 1) < (unsigned)NROWS) b = attnh[(size_t)gi * NROWS + gj + 1];
      }
      __half2 p; p.x = a; p.y = b;
      buf[r * C5D + d] = h2u(p);
    }
  }
  __syncthreads();

  int wv = tid >> 6, l = tid & 63;
  int rb = 1 + 8 * wv;   // rows rb..rb+7; 8 waves cover rows [1,65)
  int doff = 2 * l;      // dword offset (cols 4l..4l+3)
  __half2 CM0 = __float2half2_rn(1.f), CM1 = __float2half2_rn(1.f);
  if (edge) {
    float m0 = ((unsigned)(gj0 + 4 * l + 0) < (unsigned)NROWS) ? 1.f : 0.f;
    float m1 = ((unsigned)(gj0 + 4 * l + 1) < (unsigned)NROWS) ? 1.f : 0.f;
    float m2 = ((unsigned)(gj0 + 4 * l + 2) < (unsigned)NROWS) ? 1.f : 0.f;
    float m3 = ((unsigned)(gj0 + 4 * l + 3) < (unsigned)NROWS) ? 1.f : 0.f;
    CM0 = __float22half2_rn(make_float2(m0, m1));
    CM1 = __float22half2_rn(make_float2(m2, m3));
  }

  for (int p = 0; p < 10; ++p) {
    __half2 W10 = __float2half2_rn(w1p[3 * p]);
    __half2 W12 = __float2half2_rn(w1p[3 * p + 2]);
    __half2 WC  = __float2half2_rn(w1p[3 * p + 1] + w2p[3 * p + 1]);
    __half2 W20 = __float2half2_rn(w2p[3 * p]);
    __half2 W22 = __float2half2_rn(w2p[3 * p + 2]);
    __half2 AL  = __float2half2_rn(ap[p]);
    uint2 Vm = *(uint2*)&buf[(rb - 1) * C5D + doff];
    uint2 Vc = *(uint2*)&buf[rb * C5D + doff];
    uint2 dfirst, dlast;
#pragma unroll
    for (int s = 0; s < 8; ++s) {
      int r = rb + s;
      uint2 Vp = *(uint2*)&buf[(r + 1) * C5D + doff];
      unsigned Lm1 = (unsigned)__builtin_amdgcn_update_dpp(
          0, (int)Vc.y, 0x138, 0xF, 0xF, true);  // wave_shr1: lane l-1 top
      unsigned Hp1 = (unsigned)__builtin_amdgcn_update_dpp(
          0, (int)Vc.x, 0x130, 0xF, 0xF, true);  // wave_shl1: lane l+1 bottom
      unsigned SL0 = __builtin_amdgcn_alignbit(Vc.x, Lm1, 16);
      unsigned SR0 = __builtin_amdgcn_alignbit(Vc.y, Vc.x, 16);
      unsigned SR1 = __builtin_amdgcn_alignbit(Hp1, Vc.y, 16);
      __half2 o0 = __hmul2(WC, u2h(Vc.x));
      o0 = __hfma2(W10, u2h(SL0), o0);
      o0 = __hfma2(W12, u2h(SR0), o0);
      o0 = __hfma2(W20, u2h(Vm.x), o0);
      o0 = __hfma2(W22, u2h(Vp.x), o0);
      __half2 o1 = __hmul2(WC, u2h(Vc.y));
      o1 = __hfma2(W10, u2h(SR0), o1);
      o1 = __hfma2(W12, u2h(SR1), o1);
      o1 = __hfma2(W20, u2h(Vm.y), o1);
      o1 = __hfma2(W22, u2h(Vp.y), o1);
      // leaky relu = max(x, a*x), 0<a<1, via v_pk_max_f16
      {
        unsigned u0 = h2u(o0), ua0 = h2u(__hmul2(AL, o0)), r0;
        asm("v_pk_max_f16 %0, %1, %2" : "=v"(r0) : "v"(u0), "v"(ua0));
        o0 = u2h(r0);
        unsigned u1 = h2u(o1), ua1 = h2u(__hmul2(AL, o1)), r1;
        asm("v_pk_max_f16 %0, %1, %2" : "=v"(r1) : "v"(u1), "v"(ua1));
        o1 = u2h(r1);
      }
      if (edge) {
        o0 = __hmul2(o0, CM0);
        o1 = __hmul2(o1, CM1);
        if ((unsigned)(gi0 + r) >= (unsigned)NROWS) {
          o0 = __float2half2_rn(0.f);
          o1 = __float2half2_rn(0.f);
        }
      }
      uint2 res = {h2u(o0), h2u(o1)};
      if (s == 0) dfirst = res;
      else if (s == 7) dlast = res;
      else *(uint2*)&buf[r * C5D + doff] = res;  // interior: own-wave only
      Vm = Vc; Vc = Vp;
    }
    __syncthreads();  // all old-value reads complete
    *(uint2*)&buf[rb * C5D + doff] = dfirst;
    *(uint2*)&buf[(rb + 7) * C5D + doff] = dlast;
    __syncthreads();  // boundary rows visible for next layer
  }

  // ---- epilogue: masked dot over interior rows [10,56), cols [10,246) ----
  const unsigned* fin = buf;
  int i = tid >> 3;    // 0..63 (46 used)
  int part = tid & 7;  // 8 lanes per row
  int gi = gi0 + 10 + i;
  float a0 = 0.f, a1 = 0.f, a2 = 0.f, a3 = 0.f;
  if (i < C5OH && gi < NROWS) {
    const float4* op = (const float4*)opk;
    for (int g = part; g < 59; g += 8) {
      int jc = 10 + 4 * g;
      int gj = gj0 + jc;  // even, >= 0
      if (gj + 3 < NROWS) {
        unsigned d0 = fin[(10 + i) * C5D + (jc >> 1)];
        unsigned d1 = fin[(10 + i) * C5D + (jc >> 1) + 1];
        __half2 h0 = u2h(d0), h1 = u2h(d1);
        unsigned a01 = Shd[(size_t)gi * (NROWS / 2) + (gj >> 1)];
        unsigned a23 = Shd[(size_t)gi * (NROWS / 2) + (gj >> 1) + 1];
        __half2 av01 = u2h(a01), av23 = u2h(a23);
        if (__low2float(h0) > 0.f)  { float av = __low2float(av01);  float4 o = op[gj + 0]; a0 += av * o.x; a1 += av * o.y; a2 += av * o.z; a3 += av * o.w; }
        if (__high2float(h0) > 0.f) { float av = __high2float(av01); float4 o = op[gj + 1]; a0 += av * o.x; a1 += av * o.y; a2 += av * o.z; a3 += av * o.w; }
        if (__low2float(h1) > 0.f)  { float av = __low2float(av23);  float4 o = op[gj + 2]; a0 += av * o.x; a1 += av * o.y; a2 += av * o.z; a3 += av * o.w; }
        if (__high2float(h1) > 0.f) { float av = __high2float(av23); float4 o = op[gj + 3]; a0 += av * o.x; a1 += av * o.y; a2 += av * o.z; a3 += av * o.w; }
      }
    }
  }
#pragma unroll
  for (int off = 1; off < 8; off <<= 1) {
    a0 += __shfl_xor(a0, off, 64);
    a1 += __shfl_xor(a1, off, 64);
    a2 += __shfl_xor(a2, off, 64);
    a3 += __shfl_xor(a3, off, 64);
  }
  if (part == 0 && i < C5OH && gi < NROWS) {
    const float s = 1.0f / 256.0f;  // undo x256 attn staging scale
    float4 r = {a0 * s, a1 * s, a2 * s, a3 * s};
    *(float4*)&partial[((size_t)bx * NROWS + gi) * 4] = r;
  }
}

// ---------------- kernel 4: reduce 18 partials + gcn + mlp head -----------
// 8 rows per block (512 thr), one wave per row.
__global__ __launch_bounds__(512) void k_head(
    const float* __restrict__ partial, const float* __restrict__ gcn_w,
    const float* __restrict__ gcn_b, const float* __restrict__ gcn_a,
    const float* __restrict__ w1, const float* __restrict__ b1,
    const float* __restrict__ w2, const float* __restrict__ b2,
    float* __restrict__ out) {
  int t = threadIdx.x;
  int rw = t >> 6;   // 0..7 row slot (one wave each)
  int tl = t & 63;
  int row = blockIdx.x * 8 + rw;
  __shared__ float c4[8][4];
  __shared__ float gs[8][64];
  __shared__ float ms[8][32];
  {
    int c = tl & 3, gg = tl >> 2;  // gg in [0,16)
    float s = partial[((size_t)gg * NROWS + row) * 4 + c];
    if (gg < C5GX - 16)
      s += partial[((size_t)(gg + 16) * NROWS + row) * 4 + c];
#pragma unroll
    for (int off = 4; off < 64; off <<= 1) s += __shfl_xor(s, off, 64);
    if (tl < 4) c4[rw][tl] = s;
  }
  __syncthreads();
  float g = gcn_b[tl];
#pragma unroll
  for (int d = 0; d < 4; ++d) g += c4[rw][d] * gcn_w[d * 64 + tl];
  float ga = gcn_a[0];
  gs[rw][tl] = (g >= 0.f) ? g : ga * g;
  __syncthreads();
  if (tl < 32) {
    float mm = b1[tl];
#pragma unroll
    for (int i = 0; i < 64; ++i) mm += gs[rw][i] * w1[i * 32 + tl];
    ms[rw][tl] = fmaxf(mm, 0.f);
  }
  __syncthreads();
  if (tl < 4) {
    float o = b2[tl];
#pragma unroll
    for (int i = 0; i < 32; ++i) o += ms[rw][i] * w2[i * 4 + tl];
    out[row * 4 + tl] = o;
  }
}

extern "C" void kernel_launch(void* const* d_in, const int* in_sizes, int n_in,
                              void* d_out, int out_size, void* d_ws, size_t ws_size,
                              hipStream_t stream) {
  (void)in_sizes; (void)n_in; (void)out_size; (void)ws_size;
  const float* inp    = (const float*)d_in[0];
  const float* emb_w  = (const float*)d_in[1];
  const float* emb_b  = (const float*)d_in[2];
  const float* q_w    = (const float*)d_in[3];
  const float* q_b    = (const float*)d_in[4];
  const float* k_w    = (const float*)d_in[5];
  const float* k_b    = (const float*)d_in[6];
  const float* conv_w1 = (const float*)d_in[7];
  const float* conv_w2 = (const float*)d_in[8];
  const float* conv_a  = (const float*)d_in[9];
  const float* gcn_w  = (const float*)d_in[10];
  const float* gcn_b  = (const float*)d_in[11];
  const float* gcn_a  = (const float*)d_in[12];
  const float* mlp_w1 = (const float*)d_in[13];
  const float* mlp_b1 = (const float*)d_in[14];
  const float* mlp_w2 = (const float*)d_in[15];
  const float* mlp_b2 = (const float*)d_in[16];
  float* out = (float*)d_out;

  const size_t NN = (size_t)NROWS * NROWS;
  float* Sh      = (float*)d_ws;                      // fp16 attn: NN/2 floats
  float* partial = Sh + NN / 2;                       // 18*4096*4
  float* qhf     = partial + (size_t)18 * NROWS * 4;
  float* khf     = qhf + (size_t)NROWS * HID / 2;     // fp16 buffers
  float* opk     = khf + (size_t)NROWS * HID / 2;

  k_embed<<<NROWS / 4, 256, 0, stream>>>(inp, emb_w, emb_b, q_w, q_b, k_w, k_b,
                                         (__half*)qhf, (__half*)khf, opk);
  k_scores<<<NROWS / 16, 512, 0, stream>>>((const __half*)qhf,
                                           (const __half*)khf, (__half*)Sh);
  k_conv5<<<dim3(C5GX, C5GY), 512, 0, stream>>>((const __half*)Sh, partial,
                                                conv_w1, conv_w2, conv_a, opk);
  k_head<<<NROWS / 8, 512, 0, stream>>>(partial, gcn_w, gcn_b, gcn_a, mlp_w1,
                                        mlp_b1, mlp_w2, mlp_b2, out);
}